// Round 11
// baseline (127.236 us; speedup 1.0000x reference)
//
#include <hip/hip_runtime.h>
#include <hip/hip_bf16.h>
#include <stdint.h>

// Problem constants (fixed by the reference)
#define B_DIM   128
#define N_DIM   36
#define C_DIM   1024
#define KNB     16
#define NKER    8
#define OUTD    1024
#define BN_NODES (B_DIM * N_DIM)     // 4608
#define E_EDGES  (BN_NODES * KNB)    // 73728
#define PI_F 3.14159265358979323846f

// GEMM tiling R11: 64x64 tile -> 1152 blocks (4.5/CU avg, 5/CU LDS cap).
// The gemm is latency-bound (per-iter compute ~77 cyc/SIMD vs ~500 cyc DMA
// latency; depth-1 dbuf can't bridge, deeper pipes get compiler-flattened) —
// so hide latency with TLP: ~4-5 co-resident blocks interleave per CU.
#define TM 64
#define TN 64
#define BK 64
#define KIT (C_DIM / BK)   // 16
#define CLP 72             // epilogue C-tile LDS leading dim (shorts)
#define A_OFF(p) ((p) * TM * BK)                // 0 / 4096 (shorts)
#define B_OFF(p) (2 * TM * BK + (p) * TN * BK)  // 8192 / 12288 (shorts)

typedef __attribute__((ext_vector_type(8))) short bf16x8;   // 8 bf16 = 4 VGPRs
typedef __attribute__((ext_vector_type(4))) float floatx4;  // MFMA C/D frag

struct alignas(8) U16x4 { unsigned short x, y, z, w; };

__device__ __forceinline__ unsigned short f2bf(float f) {
  union { float f; uint32_t u; } v; v.f = f;
  uint32_t u = v.u;
  return (unsigned short)((u + 0x7fffu + ((u >> 16) & 1u)) >> 16);  // RNE
}
__device__ __forceinline__ float bf2f_lo(uint32_t pair) {
  union { uint32_t u; float f; } v; v.u = pair << 16;
  return v.f;
}
__device__ __forceinline__ float bf2f_hi(uint32_t pair) {
  union { uint32_t u; float f; } v; v.u = pair & 0xffff0000u;
  return v.f;
}

// async global -> LDS, 16B per lane (global_load_lds_dwordx4).
__device__ __forceinline__ void gload16(const void* g, void* l) {
  __builtin_amdgcn_global_load_lds((__attribute__((address_space(1))) void*)(g),
                                   (__attribute__((address_space(3))) void*)(l),
                                   16, 0, 0);
}

// ---------------------------------------------------------------------------
// Kernel 1: cast node_feats and conv_w (both fp32) to bf16  (R8-verified)
// ---------------------------------------------------------------------------
__global__ __launch_bounds__(256)
void cast_kernel(const float* __restrict__ feats,    // [BN*1024]
                 const float* __restrict__ cw,       // [1024*1024]
                 unsigned short* __restrict__ fb,
                 unsigned short* __restrict__ wb)
{
  const int NF4 = (BN_NODES * C_DIM) / 4;   // 1179648
  const int NW4 = (C_DIM * OUTD) / 4;       // 262144
  int tid = blockIdx.x * 256 + threadIdx.x;
  if (tid < NF4) {
    float4 v = ((const float4*)feats)[tid];
    U16x4 o = { f2bf(v.x), f2bf(v.y), f2bf(v.z), f2bf(v.w) };
    ((U16x4*)fb)[tid] = o;
  } else {
    int t = tid - NF4;
    if (t < NW4) {
      float4 v = ((const float4*)cw)[t];
      U16x4 o = { f2bf(v.x), f2bf(v.y), f2bf(v.z), f2bf(v.w) };
      ((U16x4*)wb)[t] = o;
    }
  }
}

// ---------------------------------------------------------------------------
// Kernel 2: proj = fb @ wb^T  [4608,1024] x [1024,1024]^T, bf16 MFMA.
// 64x64 tile, 4 waves as 2x2 (32x32 each), dbuf BK=64, XOR swizzle,
// LDS-staged coalesced epilogue. 1152 blocks for TLP latency hiding.
// ---------------------------------------------------------------------------
__global__ __launch_bounds__(256)
void gemm_bt(const unsigned short* __restrict__ A,    // [4608][1024] bf16
             const unsigned short* __restrict__ Bt,   // [1024][1024] bf16
             unsigned short* __restrict__ D)          // [4608][1024] bf16
{
  __shared__ unsigned short smem[4 * TM * BK];  // 32 KB: A0,A1,B0,B1

  const int tid  = threadIdx.x;
  const int lane = tid & 63;
  const int wave = tid >> 6;
  const int wm   = wave >> 1;       // wave row (0..1) -> 32 rows each
  const int wn   = wave & 1;        // wave col (0..1) -> 32 cols each
  const int row0 = blockIdx.x * TM;
  const int col0 = blockIdx.y * TN;

  const int q  = lane >> 4;         // quad
  const int lr = lane & 15;

  floatx4 acc[2][2] = {};

  // staging maps: tile = 64 rows x 8 chunks (16B) = 512 chunks; thread t
  // handles chunks c = t, t+256 for A and for B. LDS addr = c*16 (DMA
  // constraint). Global column XOR-swizzled: LDS (row,qc) <- global qc^(row&7).
  int offA[2], offB[2];
#pragma unroll
  for (int i = 0; i < 2; ++i) {
    int c = tid + 256 * i, row = c >> 3, qc = c & 7;
    offA[i] = (row0 + row) * C_DIM + (qc ^ (row & 7)) * 8;
    offB[i] = (col0 + row) * C_DIM + (qc ^ (row & 7)) * 8;
  }

#define DMA(T, P) do {                                                       \
    _Pragma("unroll") for (int i = 0; i < 2; ++i) {                          \
      gload16(A  + offA[i] + (T) * BK,                                       \
              &smem[A_OFF(P) + (tid + 256 * i) * 8]);                        \
      gload16(Bt + offB[i] + (T) * BK,                                       \
              &smem[B_OFF(P) + (tid + 256 * i) * 8]);                        \
    }                                                                        \
  } while (0)

  DMA(0, 0);   // prologue: tile 0 into buf 0

  for (int t = 0; t < KIT; ++t) {
    const int p = t & 1;
    __syncthreads();                  // vmcnt(0): waits DMA(t) — TLP-hidden
    if (t + 1 < KIT) DMA(t + 1, 1 - p);

    const int aBase = A_OFF(p);
    const int bBase = B_OFF(p);
#pragma unroll
    for (int kc = 0; kc < 2; ++kc) {
      // frag (row r, chunk kc*4+q) at swizzled chunk ((kc*4+q)^(lr&7))
      const int sc = ((kc * 4 + q) ^ (lr & 7)) * 8;
      bf16x8 af[2], bfr[2];
#pragma unroll
      for (int i = 0; i < 2; ++i) {
        af[i]  = *(const bf16x8*)&smem[aBase + (wm * 32 + i * 16 + lr) * BK + sc];
        bfr[i] = *(const bf16x8*)&smem[bBase + (wn * 32 + i * 16 + lr) * BK + sc];
      }
#pragma unroll
      for (int i = 0; i < 2; ++i)
#pragma unroll
        for (int j = 0; j < 2; ++j)
          acc[i][j] = __builtin_amdgcn_mfma_f32_16x16x32_bf16(
              af[i], bfr[j], acc[i][j], 0, 0, 0);
    }
  }
#undef DMA

  // ---- epilogue: stage C tile (64x64 bf16) in LDS, coalesced stores ----
  __syncthreads();
#pragma unroll
  for (int i = 0; i < 2; ++i)
#pragma unroll
    for (int j = 0; j < 2; ++j)
#pragma unroll
      for (int r = 0; r < 4; ++r)
        smem[(wm * 32 + i * 16 + q * 4 + r) * CLP + wn * 32 + j * 16 + lr] =
            f2bf(acc[i][j][r]);
  __syncthreads();
  // full tile = 64 rows x 8 chunks = 512 chunks; thread t does 2
#pragma unroll
  for (int i = 0; i < 2; ++i) {
    int c = tid + 256 * i;
    int row = c >> 3, qc = c & 7;
    *(uint4*)&D[(size_t)(row0 + row) * OUTD + col0 + qc * 8] =
        *(const uint4*)&smem[row * CLP + qc * 8];
  }
}

// ---------------------------------------------------------------------------
// Kernel 3: fused edge-weight + aggregate, 2 nodes per block (R8-verified).
// ---------------------------------------------------------------------------
__global__ __launch_bounds__(256)
void agg_fused(const unsigned short* __restrict__ proj,  // [BN][1024] bf16
               const float* __restrict__ centre,         // [BN][2]
               const int*   __restrict__ nbr,            // [BN][16]
               const float* __restrict__ gw,             // [E]
               const float* __restrict__ mrho,
               const float* __restrict__ mth,
               const float* __restrict__ prho,
               const float* __restrict__ pth,
               float* __restrict__ out)                  // [BN][1024] fp32
{
  __shared__ int   idx[2][KNB];
  __shared__ float nxy[2][KNB][2];
  __shared__ float cxy[2][2];
  __shared__ float wk[2][KNB][NKER];
  __shared__ float scl[2][KNB];
  __shared__ float ew[2][NKER][KNB];

  const int n0   = blockIdx.x * 2;
  const int t    = threadIdx.x;
  const int half = t >> 7;
  const int u    = t & 127;

  if (t < 32) {
    int h = t >> 4, j = t & 15;
    int m = nbr[(n0 + h) * KNB + j];
    idx[h][j] = m;
    nxy[h][j][0] = centre[2 * m];
    nxy[h][j][1] = centre[2 * m + 1];
  } else if (t < 34) {
    int h = t - 32;
    cxy[h][0] = centre[2 * (n0 + h)];
    cxy[h][1] = centre[2 * (n0 + h) + 1];
  }
  __syncthreads();

  {                                    // 2 nodes x 16 edges x 8 kernels
    int j = u >> 3, k = u & 7;
    float cx = cxy[half][0] - nxy[half][j][0];
    float cy = cxy[half][1] - nxy[half][j][1];
    float rho   = sqrtf(cx * cx + cy * cy);
    float theta = atan2f(cx, cy);      // jnp.arctan2(coord_x, coord_y)
    float dr = rho - mrho[k];
    float pr = prho[k];
    float w_r = expf(-0.5f * dr * dr / (1e-14f + pr * pr));
    float fa = fabsf(theta - mth[k]);
    float sa = fabsf(2.0f * PI_F - fa);
    float mm = fminf(fa, sa);
    float pt = pth[k];
    float w_t = expf(-0.5f * mm * mm / (1e-14f + pt * pt));
    float ww = w_r * w_t;
    wk[half][j][k] = (ww != ww) ? 0.f : ww;   // NaN guard (reference parity)
  }
  __syncthreads();

  if (u < KNB) {
    float s = 0.f;
#pragma unroll
    for (int k = 0; k < NKER; ++k) s += wk[half][u][k];
    scl[half][u] = gw[(n0 + half) * KNB + u] / s;
  }
  __syncthreads();

  {
    int j = u >> 3, k = u & 7;
    ew[half][k][j] = wk[half][j][k] * scl[half][j];
  }
  __syncthreads();

  // main aggregate: thread u -> channels 8u..8u+7 (kernel block k = u/16)
  const int n = n0 + half;
  const int k = u >> 4;
  float a[8] = {0.f, 0.f, 0.f, 0.f, 0.f, 0.f, 0.f, 0.f};
#pragma unroll
  for (int j = 0; j < KNB; ++j) {
    float wv = ew[half][k][j];
    uint4 v = *(const uint4*)&proj[(size_t)idx[half][j] * OUTD + u * 8];
    a[0] += wv * bf2f_lo(v.x);  a[1] += wv * bf2f_hi(v.x);
    a[2] += wv * bf2f_lo(v.y);  a[3] += wv * bf2f_hi(v.y);
    a[4] += wv * bf2f_lo(v.z);  a[5] += wv * bf2f_hi(v.z);
    a[6] += wv * bf2f_lo(v.w);  a[7] += wv * bf2f_hi(v.w);
  }
  float4 r0, r1;
  r0.x = fmaxf(a[0], 0.f); r0.y = fmaxf(a[1], 0.f);
  r0.z = fmaxf(a[2], 0.f); r0.w = fmaxf(a[3], 0.f);
  r1.x = fmaxf(a[4], 0.f); r1.y = fmaxf(a[5], 0.f);
  r1.z = fmaxf(a[6], 0.f); r1.w = fmaxf(a[7], 0.f);
  float* o = out + (size_t)n * OUTD + u * 8;
  *(float4*)(o)     = r0;
  *(float4*)(o + 4) = r1;
}

// ---------------------------------------------------------------------------
extern "C" void kernel_launch(void* const* d_in, const int* in_sizes, int n_in,
                              void* d_out, int out_size, void* d_ws, size_t ws_size,
                              hipStream_t stream)
{
  const float* feats  = (const float*)d_in[0];   // [128,36,1024]
  const float* centre = (const float*)d_in[1];   // [128,36,2]
  const int*   nbr    = (const int*)  d_in[2];   // [4608,16]
  const float* gw     = (const float*)d_in[3];   // [73728,1]
  const float* mrho   = (const float*)d_in[4];
  const float* mth    = (const float*)d_in[5];
  const float* prho   = (const float*)d_in[6];
  const float* pth    = (const float*)d_in[7];
  const float* cw     = (const float*)d_in[8];   // [8,128,1024] == [1024,1024]
  float* out = (float*)d_out;

  // workspace layout (total 20 MB)
  char* ws = (char*)d_ws;
  unsigned short* fb   = (unsigned short*)(ws);              //  9,437,184 B
  unsigned short* wb   = (unsigned short*)(ws + 9437184);    //  2,097,152 B
  unsigned short* proj = (unsigned short*)(ws + 11534336);   //  9,437,184 B

  cast_kernel<<<dim3(((BN_NODES * C_DIM) / 4 + (C_DIM * OUTD) / 4) / 256),
                dim3(256), 0, stream>>>(feats, cw, fb, wb);
  gemm_bt<<<dim3(BN_NODES / TM, OUTD / TN), dim3(256), 0, stream>>>(fb, wb, proj);
  agg_fused<<<dim3(BN_NODES / 2), dim3(256), 0, stream>>>(
      proj, centre, nbr, gw, mrho, mth, prho, pth, out);
}

// Round 12
// 122.205 us; speedup vs baseline: 1.0412x; 1.0412x over previous
//
#include <hip/hip_runtime.h>
#include <hip/hip_bf16.h>
#include <stdint.h>

// Problem constants (fixed by the reference)
#define B_DIM   128
#define N_DIM   36
#define C_DIM   1024
#define KNB     16
#define NKER    8
#define OUTD    1024
#define BN_NODES (B_DIM * N_DIM)     // 4608
#define E_EDGES  (BN_NODES * KNB)    // 73728
#define PI_F 3.14159265358979323846f

// GEMM tiling (R8-verified optimum): 64x128 tile (576 blocks, 2.25/CU),
// BK=64, double-buffered DMA, one barrier per iter, XOR swizzle,
// LDS-staged coalesced epilogue. R11's 64x64 TLP variant regressed
// (double B traffic); R10's in-gemm A-cast regressed (vmcnt in loop body).
#define TM 64
#define TN 128
#define BK 64
#define KIT (C_DIM / BK)   // 16
#define CLP 136            // epilogue C-tile LDS leading dim
#define A_OFF(p) ((p) * TM * BK)                // 0 / 4096
#define B_OFF(p) (2 * TM * BK + (p) * TN * BK)  // 8192 / 16384

typedef __attribute__((ext_vector_type(8))) short bf16x8;   // 8 bf16 = 4 VGPRs
typedef __attribute__((ext_vector_type(4))) float floatx4;  // MFMA C/D frag

struct alignas(8) U16x4 { unsigned short x, y, z, w; };

__device__ __forceinline__ unsigned short f2bf(float f) {
  union { float f; uint32_t u; } v; v.f = f;
  uint32_t u = v.u;
  return (unsigned short)((u + 0x7fffu + ((u >> 16) & 1u)) >> 16);  // RNE
}
__device__ __forceinline__ float bf2f_lo(uint32_t pair) {
  union { uint32_t u; float f; } v; v.u = pair << 16;
  return v.f;
}
__device__ __forceinline__ float bf2f_hi(uint32_t pair) {
  union { uint32_t u; float f; } v; v.u = pair & 0xffff0000u;
  return v.f;
}

// async global -> LDS, 16B per lane (global_load_lds_dwordx4).
// LDS side MUST be wave-uniform base + lane*16; global side may scatter.
__device__ __forceinline__ void gload16(const void* g, void* l) {
  __builtin_amdgcn_global_load_lds((__attribute__((address_space(1))) void*)(g),
                                   (__attribute__((address_space(3))) void*)(l),
                                   16, 0, 0);
}

// ---------------------------------------------------------------------------
// Kernel 1: cast node_feats and conv_w (both fp32) to bf16
// ---------------------------------------------------------------------------
__global__ __launch_bounds__(256)
void cast_kernel(const float* __restrict__ feats,    // [BN*1024]
                 const float* __restrict__ cw,       // [1024*1024]
                 unsigned short* __restrict__ fb,
                 unsigned short* __restrict__ wb)
{
  const int NF4 = (BN_NODES * C_DIM) / 4;   // 1179648
  const int NW4 = (C_DIM * OUTD) / 4;       // 262144
  int tid = blockIdx.x * 256 + threadIdx.x;
  if (tid < NF4) {
    float4 v = ((const float4*)feats)[tid];
    U16x4 o = { f2bf(v.x), f2bf(v.y), f2bf(v.z), f2bf(v.w) };
    ((U16x4*)fb)[tid] = o;
  } else {
    int t = tid - NF4;
    if (t < NW4) {
      float4 v = ((const float4*)cw)[t];
      U16x4 o = { f2bf(v.x), f2bf(v.y), f2bf(v.z), f2bf(v.w) };
      ((U16x4*)wb)[t] = o;
    }
  }
}

// ---------------------------------------------------------------------------
// Kernel 2: proj = fb @ wb^T  [4608,1024] x [1024,1024]^T, bf16 MFMA.
// 64x128 tile, 4 waves as 2x2 (32x64 each), dbuf BK=64, XOR swizzle,
// LDS-staged coalesced epilogue.
// ---------------------------------------------------------------------------
__global__ __launch_bounds__(256)
void gemm_bt(const unsigned short* __restrict__ A,    // [4608][1024] bf16
             const unsigned short* __restrict__ Bt,   // [1024][1024] bf16
             unsigned short* __restrict__ D)          // [4608][1024] bf16
{
  __shared__ unsigned short smem[2 * TM * BK + 2 * TN * BK];  // 48 KB

  const int tid  = threadIdx.x;
  const int lane = tid & 63;
  const int wave = tid >> 6;
  const int wm   = wave >> 1;       // wave row (0..1) -> 32 rows each
  const int wn   = wave & 1;        // wave col (0..1) -> 64 cols each
  const int row0 = blockIdx.x * TM;
  const int col0 = blockIdx.y * TN;

  const int q  = lane >> 4;         // quad
  const int lr = lane & 15;

  floatx4 acc[2][4] = {};

  // staging maps (16B chunks, chunk c -> row c>>3, qcol c&7, XOR swizzle):
  // A tile 64x8 chunks = 512 -> thread t does c = t + 256*i, i<2
  // B tile 128x8 chunks = 1024 -> c = t + 256*i, i<4
  int offA[2], offB[4];
#pragma unroll
  for (int i = 0; i < 2; ++i) {
    int c = tid + 256 * i, row = c >> 3, qc = c & 7;
    offA[i] = (row0 + row) * C_DIM + (qc ^ (row & 7)) * 8;
  }
#pragma unroll
  for (int i = 0; i < 4; ++i) {
    int c = tid + 256 * i, row = c >> 3, qc = c & 7;
    offB[i] = (col0 + row) * C_DIM + (qc ^ (row & 7)) * 8;
  }

#define DMA(T, P) do {                                                       \
    _Pragma("unroll") for (int i = 0; i < 2; ++i)                            \
      gload16(A + offA[i] + (T) * BK,                                        \
              &smem[A_OFF(P) + (tid + 256 * i) * 8]);                        \
    _Pragma("unroll") for (int i = 0; i < 4; ++i)                            \
      gload16(Bt + offB[i] + (T) * BK,                                       \
              &smem[B_OFF(P) + (tid + 256 * i) * 8]);                        \
  } while (0)

  DMA(0, 0);   // prologue: tile 0 into buf 0

  for (int t = 0; t < KIT; ++t) {
    const int p = t & 1;
    __syncthreads();                  // vmcnt(0): waits DMA(t) — overlapped
    if (t + 1 < KIT) DMA(t + 1, 1 - p);

    const int aBase = A_OFF(p);
    const int bBase = B_OFF(p);
#pragma unroll
    for (int kc = 0; kc < 2; ++kc) {
      // frag (row r, chunk kc*4+q) at swizzled chunk ((kc*4+q)^(r&7));
      // r mod 8 == lr mod 8 for all frag rows -> sc = (kc*4+q)^(lr&7).
      const int sc = ((kc * 4 + q) ^ (lr & 7)) * 8;
      bf16x8 af[2], bfr[4];
#pragma unroll
      for (int i = 0; i < 2; ++i)
        af[i]  = *(const bf16x8*)&smem[aBase + (wm * 32 + i * 16 + lr) * BK + sc];
#pragma unroll
      for (int j = 0; j < 4; ++j)
        bfr[j] = *(const bf16x8*)&smem[bBase + (wn * 64 + j * 16 + lr) * BK + sc];
#pragma unroll
      for (int i = 0; i < 2; ++i)
#pragma unroll
        for (int j = 0; j < 4; ++j)
          acc[i][j] = __builtin_amdgcn_mfma_f32_16x16x32_bf16(
              af[i], bfr[j], acc[i][j], 0, 0, 0);
    }
  }
#undef DMA

  // ---- epilogue: stage C tile (64x128 bf16) in LDS, coalesced stores ----
  __syncthreads();
#pragma unroll
  for (int i = 0; i < 2; ++i)
#pragma unroll
    for (int j = 0; j < 4; ++j)
#pragma unroll
      for (int r = 0; r < 4; ++r)
        smem[(wm * 32 + i * 16 + q * 4 + r) * CLP + wn * 64 + j * 16 + lr] =
            f2bf(acc[i][j][r]);
  __syncthreads();
  // full tile = 64 rows x 16 chunks = 1024 chunks; thread t does 4
#pragma unroll
  for (int i = 0; i < 4; ++i) {
    int c = tid + 256 * i;
    int row = c >> 4, qc = c & 15;
    *(uint4*)&D[(size_t)(row0 + row) * OUTD + col0 + qc * 8] =
        *(const uint4*)&smem[row * CLP + qc * 8];
  }
}

// ---------------------------------------------------------------------------
// Kernel 3: fused edge-weight + aggregate, 2 nodes per block.
// Threads 0-127 -> node 2b, 128-255 -> node 2b+1; thread u (=t&127) owns
// channels 8u..8u+7 (one uint4 gather per neighbor).
// ---------------------------------------------------------------------------
__global__ __launch_bounds__(256)
void agg_fused(const unsigned short* __restrict__ proj,  // [BN][1024] bf16
               const float* __restrict__ centre,         // [BN][2]
               const int*   __restrict__ nbr,            // [BN][16]
               const float* __restrict__ gw,             // [E]
               const float* __restrict__ mrho,
               const float* __restrict__ mth,
               const float* __restrict__ prho,
               const float* __restrict__ pth,
               float* __restrict__ out)                  // [BN][1024] fp32
{
  __shared__ int   idx[2][KNB];
  __shared__ float nxy[2][KNB][2];
  __shared__ float cxy[2][2];
  __shared__ float wk[2][KNB][NKER];
  __shared__ float scl[2][KNB];
  __shared__ float ew[2][NKER][KNB];

  const int n0   = blockIdx.x * 2;
  const int t    = threadIdx.x;
  const int half = t >> 7;
  const int u    = t & 127;

  if (t < 32) {
    int h = t >> 4, j = t & 15;
    int m = nbr[(n0 + h) * KNB + j];
    idx[h][j] = m;
    nxy[h][j][0] = centre[2 * m];
    nxy[h][j][1] = centre[2 * m + 1];
  } else if (t < 34) {
    int h = t - 32;
    cxy[h][0] = centre[2 * (n0 + h)];
    cxy[h][1] = centre[2 * (n0 + h) + 1];
  }
  __syncthreads();

  {                                    // 2 nodes x 16 edges x 8 kernels
    int j = u >> 3, k = u & 7;
    float cx = cxy[half][0] - nxy[half][j][0];
    float cy = cxy[half][1] - nxy[half][j][1];
    float rho   = sqrtf(cx * cx + cy * cy);
    float theta = atan2f(cx, cy);      // jnp.arctan2(coord_x, coord_y)
    float dr = rho - mrho[k];
    float pr = prho[k];
    float w_r = expf(-0.5f * dr * dr / (1e-14f + pr * pr));
    float fa = fabsf(theta - mth[k]);
    float sa = fabsf(2.0f * PI_F - fa);
    float mm = fminf(fa, sa);
    float pt = pth[k];
    float w_t = expf(-0.5f * mm * mm / (1e-14f + pt * pt));
    float ww = w_r * w_t;
    wk[half][j][k] = (ww != ww) ? 0.f : ww;   // NaN guard (reference parity)
  }
  __syncthreads();

  if (u < KNB) {
    float s = 0.f;
#pragma unroll
    for (int k = 0; k < NKER; ++k) s += wk[half][u][k];
    scl[half][u] = gw[(n0 + half) * KNB + u] / s;
  }
  __syncthreads();

  {
    int j = u >> 3, k = u & 7;
    ew[half][k][j] = wk[half][j][k] * scl[half][j];
  }
  __syncthreads();

  // main aggregate: thread u -> channels 8u..8u+7 (kernel block k = u/16)
  const int n = n0 + half;
  const int k = u >> 4;
  float a[8] = {0.f, 0.f, 0.f, 0.f, 0.f, 0.f, 0.f, 0.f};
#pragma unroll
  for (int j = 0; j < KNB; ++j) {
    float wv = ew[half][k][j];
    uint4 v = *(const uint4*)&proj[(size_t)idx[half][j] * OUTD + u * 8];
    a[0] += wv * bf2f_lo(v.x);  a[1] += wv * bf2f_hi(v.x);
    a[2] += wv * bf2f_lo(v.y);  a[3] += wv * bf2f_hi(v.y);
    a[4] += wv * bf2f_lo(v.z);  a[5] += wv * bf2f_hi(v.z);
    a[6] += wv * bf2f_lo(v.w);  a[7] += wv * bf2f_hi(v.w);
  }
  float4 r0, r1;
  r0.x = fmaxf(a[0], 0.f); r0.y = fmaxf(a[1], 0.f);
  r0.z = fmaxf(a[2], 0.f); r0.w = fmaxf(a[3], 0.f);
  r1.x = fmaxf(a[4], 0.f); r1.y = fmaxf(a[5], 0.f);
  r1.z = fmaxf(a[6], 0.f); r1.w = fmaxf(a[7], 0.f);
  float* o = out + (size_t)n * OUTD + u * 8;
  *(float4*)(o)     = r0;
  *(float4*)(o + 4) = r1;
}

// ---------------------------------------------------------------------------
extern "C" void kernel_launch(void* const* d_in, const int* in_sizes, int n_in,
                              void* d_out, int out_size, void* d_ws, size_t ws_size,
                              hipStream_t stream)
{
  const float* feats  = (const float*)d_in[0];   // [128,36,1024]
  const float* centre = (const float*)d_in[1];   // [128,36,2]
  const int*   nbr    = (const int*)  d_in[2];   // [4608,16]
  const float* gw     = (const float*)d_in[3];   // [73728,1]
  const float* mrho   = (const float*)d_in[4];
  const float* mth    = (const float*)d_in[5];
  const float* prho   = (const float*)d_in[6];
  const float* pth    = (const float*)d_in[7];
  const float* cw     = (const float*)d_in[8];   // [8,128,1024] == [1024,1024]
  float* out = (float*)d_out;

  // workspace layout (total 20 MB)
  char* ws = (char*)d_ws;
  unsigned short* fb   = (unsigned short*)(ws);              //  9,437,184 B
  unsigned short* wb   = (unsigned short*)(ws + 9437184);    //  2,097,152 B
  unsigned short* proj = (unsigned short*)(ws + 11534336);   //  9,437,184 B

  cast_kernel<<<dim3(((BN_NODES * C_DIM) / 4 + (C_DIM * OUTD) / 4) / 256),
                dim3(256), 0, stream>>>(feats, cw, fb, wb);
  gemm_bt<<<dim3(BN_NODES / TM, OUTD / TN), dim3(256), 0, stream>>>(fb, wb, proj);
  agg_fused<<<dim3(BN_NODES / 2), dim3(256), 0, stream>>>(
      proj, centre, nbr, gw, mrho, mth, prho, pth, out);
}